// Round 4
// baseline (1978.273 us; speedup 1.0000x reference)
//
#include <hip/hip_runtime.h>

// ODEBlock1D RK4, B=32 L=8192 C=64, 8 steps × 4 fused evals per kernel.
// Waves split rows×co-halves; RK4 acc in registers; y re-read from global per
// eval (L2-resident); z (bf16 conv input) ping-pongs in LDS. Eval loop is
// NOT unrolled (unroll 1) to keep live ranges short -> no scratch spill.

#define BB 32
#define LL 8192
#define CC 64
#define TILE 120         // central rows stored per block
#define NBLK 69          // ceil(8192/120)
#define BUFR 130         // 128 compute rows + 2 conv-pad rows
#define ZST 72           // bf16 row stride (64 + 8 pad shorts) = 144 B
#define THREADS 256

typedef __attribute__((ext_vector_type(8))) short bf16x8;
typedef __attribute__((ext_vector_type(4))) float f32x4;

__device__ __forceinline__ unsigned bf_rne(float f) {
    unsigned u = __float_as_uint(f);
    return u + 0x7fffu + ((u >> 16) & 1u);   // bf16 RNE in high 16 bits
}
__device__ __forceinline__ unsigned pack_bf16(float a, float b) {
    return (bf_rne(a) >> 16) | (bf_rne(b) & 0xffff0000u);
}
__device__ __forceinline__ short bf16_of(float f) { return (short)(bf_rne(f) >> 16); }

__launch_bounds__(THREADS, 3)
__global__ void step_kernel(const float* __restrict__ y_in, float* __restrict__ y_out,
                            const float* __restrict__ w, const float* __restrict__ bias,
                            float t0, float h)
{
    __shared__ unsigned short zA[BUFR * ZST];
    __shared__ unsigned short zB[BUFR * ZST];

    const int tid = threadIdx.x;
    const int b = blockIdx.y;
    const int l0 = blockIdx.x * TILE;
    const int lane = tid & 63;
    const int wv = tid >> 6;
    const int ch = wv >> 1;            // co half
    const int bset = wv & 1;           // band set: bands bset*4 .. bset*4+3
    const int g = lane >> 4;
    const int ml = lane & 15;
    const int co = ch * 32 + 2 * ml;   // lane's adjacent co pair
    const bool edge = (blockIdx.x == 0) || (blockIdx.x == NBLK - 1);

    // valid compute-row range (r in [0,128), l = l0-4+r in [0,LL))
    const int rmin = (l0 == 0) ? 4 : 0;
    const int rmax = min(128, LL - l0 + 4);

    // zero conv-pad rows (br = 0 and 129) of both buffers — never rewritten
    if (tid < 64) {
        zA[tid] = 0; zA[129 * ZST + tid] = 0;
        zB[tid] = 0; zB[129 * ZST + tid] = 0;
    }

    // ---- B fragments: w -> bf16 RNE; chunk c: kw=c>>1, ci=(c&1)*32+g*8+j ----
    bf16x8 Bf[6][2];
#pragma unroll
    for (int c = 0; c < 6; c++) {
        const float* wp = w + (c >> 1) * (65 * CC) + (((c & 1) * 32) + g * 8) * CC + co;
#pragma unroll
        for (int j = 0; j < 8; j++) {
            float2 v = *(const float2*)(wp + j * CC);
            Bf[c][0][j] = bf16_of(v.x);
            Bf[c][1][j] = bf16_of(v.y);
        }
    }
    const float2 wt0 = *(const float2*)(w + 0 * (65 * CC) + CC * CC + co);
    const float2 wt1 = *(const float2*)(w + 1 * (65 * CC) + CC * CC + co);
    const float2 wt2 = *(const float2*)(w + 2 * (65 * CC) + CC * CC + co);
    const float2 bv  = *(const float2*)(bias + co);

    // per-thread base pointer into this block's y tile (row r at yb + r*CC)
    const float* __restrict__ yb = y_in + ((size_t)b * LL + (size_t)(l0 - 4)) * CC + co;

    // ---- stage z0 = bf16(y) into zA ----
#pragma unroll
    for (int bb = 0; bb < 4; bb++) {
        const int r0 = (bset * 4 + bb) * 16;
#pragma unroll
        for (int i = 0; i < 4; i++) {
            const int r = r0 + g * 4 + i;
            float2 v = make_float2(0.f, 0.f);
            if (r >= rmin && r < rmax) v = *(const float2*)(yb + (size_t)r * CC);
            *(unsigned*)&zA[(r + 1) * ZST + co] = pack_bf16(v.x, v.y);
        }
    }
    __syncthreads();

    float2 aR[4][4];
    const float ca[4]  = {h / 6.f, h / 3.f, h / 3.f, h / 6.f};
    const float cuv[4] = {0.5f * h, 0.5f * h, h, 0.f};
    const float tof[4] = {0.f, 0.5f * h, 0.5f * h, h};

#pragma unroll 1
    for (int e = 0; e < 4; e++) {
        const unsigned short* zin = (e & 1) ? zB : zA;
        unsigned short* zout = (e & 1) ? zA : zB;
        const float t = t0 + tof[e];
        const float cacc = ca[e], cuu = cuv[e];
        const float2 tb = {t * (wt0.x + wt1.x + wt2.x) + bv.x,
                           t * (wt0.y + wt1.y + wt2.y) + bv.y};

#pragma unroll
        for (int bb = 0; bb < 4; bb++) {
            const int r0 = (bset * 4 + bb) * 16;
            f32x4 acc0 = {0.f, 0.f, 0.f, 0.f};
            f32x4 acc1 = {0.f, 0.f, 0.f, 0.f};
#pragma unroll
            for (int c = 0; c < 6; c++) {
                const int br = r0 + ml + (c >> 1);   // A row + 1 (pad offset)
                const bf16x8 a =
                    *(const bf16x8*)&zin[br * ZST + ((c & 1) * 32) + g * 8];
                acc0 = __builtin_amdgcn_mfma_f32_16x16x32_bf16(a, Bf[c][0], acc0, 0, 0, 0);
                acc1 = __builtin_amdgcn_mfma_f32_16x16x32_bf16(a, Bf[c][1], acc1, 0, 0, 0);
            }
#pragma unroll
            for (int i = 0; i < 4; i++) {
                const int r = r0 + g * 4 + i;
                float k0 = acc0[i] + tb.x;
                float k1 = acc1[i] + tb.y;
                if (edge) {
                    const int l = l0 - 4 + r;
                    if (l == 0)      { k0 -= t * wt0.x; k1 -= t * wt0.y; }
                    if (l == LL - 1) { k0 -= t * wt2.x; k1 -= t * wt2.y; }
                }
                k0 = fmaxf(k0, 0.f);
                k1 = fmaxf(k1, 0.f);
                // fresh y read each eval (L2-resident after eval 0)
                float2 y2 = make_float2(0.f, 0.f);
                const bool ok = (r >= rmin) && (r < rmax);
                if (ok) y2 = *(const float2*)(yb + (size_t)r * CC);
                if (e == 0) {
                    aR[bb][i].x = y2.x + cacc * k0;
                    aR[bb][i].y = y2.y + cacc * k1;
                } else {
                    aR[bb][i].x += cacc * k0;
                    aR[bb][i].y += cacc * k1;
                }
                if (e < 3) {
                    float u0 = 0.f, u1 = 0.f;
                    if (ok) {            // keep seq-boundary rows zero in z
                        u0 = y2.x + cuu * k0;
                        u1 = y2.y + cuu * k1;
                    }
                    *(unsigned*)&zout[(r + 1) * ZST + co] = pack_bf16(u0, u1);
                }
            }
        }
        if (e < 3) __syncthreads();
    }

    // ---- store central rows (r in [4,124)) ----
#pragma unroll
    for (int bb = 0; bb < 4; bb++) {
        const int r0 = (bset * 4 + bb) * 16;
#pragma unroll
        for (int i = 0; i < 4; i++) {
            const int r = r0 + g * 4 + i;
            if (r >= 4 && r < 124 && r < rmax) {
                const int l = l0 - 4 + r;
                *(float2*)(y_out + ((size_t)b * LL + l) * CC + co) = aR[bb][i];
            }
        }
    }
}

extern "C" void kernel_launch(void* const* d_in, const int* in_sizes, int n_in,
                              void* d_out, int out_size, void* d_ws, size_t ws_size,
                              hipStream_t stream) {
    const float* x = (const float*)d_in[0];
    const float* w = (const float*)d_in[1];
    const float* bias = (const float*)d_in[2];
    float* out = (float*)d_out;
    float* P0 = (float*)d_ws;   // 32*8192*64*4 = 67.1 MB scratch
    const float h = 1.0f / 8.0f;

    dim3 grid(NBLK, BB), block(THREADS);
    for (int s = 0; s < 8; s++) {
        const float* yin = (s == 0) ? x : ((s & 1) ? P0 : out);
        float* yout = (s & 1) ? out : P0;   // step 7 writes `out`
        step_kernel<<<grid, block, 0, stream>>>(yin, yout, w, bias, s * h, h);
    }
}

// Round 5
// 594.012 us; speedup vs baseline: 3.3304x; 3.3304x over previous
//
#include <hip/hip_runtime.h>

// ODEBlock1D RK4, B=32 L=8192 C=64, 8 steps × 4 fused evals per kernel.
// R2 chassis (ys fp32 in LDS, small reg acc, unroll-1 eval loop) + R3 layout
// (wave = co-half × row-half -> 2x less A-frag LDS traffic; pair-co mapping
// -> packed b32 z writes, conflict-free). Plain bf16 weights (no hi/lo split).

#define BB 32
#define LL 8192
#define CC 64
#define TILE 88          // central rows stored per block
#define NBLK 94          // ceil(8192/88)
#define CROWS 96         // compute rows (6 MFMA bands), r -> l = l0-4+r
#define BUFR 98          // + 2 conv-pad rows (z row = r+1)
#define ZST 72           // shorts per z row (144 B, 16B-aligned rows)
#define YST 66           // floats per ys row
#define THREADS 256

typedef __attribute__((ext_vector_type(8))) short bf16x8;
typedef __attribute__((ext_vector_type(4))) float f32x4;

__device__ __forceinline__ unsigned bf_rne(float f) {
    unsigned u = __float_as_uint(f);
    return u + 0x7fffu + ((u >> 16) & 1u);   // bf16 RNE in high 16 bits
}
__device__ __forceinline__ unsigned pack_bf16(float a, float b) {
    return (bf_rne(a) >> 16) | (bf_rne(b) & 0xffff0000u);
}
__device__ __forceinline__ short bf16_of(float f) { return (short)(bf_rne(f) >> 16); }

__launch_bounds__(THREADS, 3)
__global__ void step_kernel(const float* __restrict__ y_in, float* __restrict__ y_out,
                            const float* __restrict__ w, const float* __restrict__ bias,
                            float t0, float h)
{
    __shared__ unsigned short zA[BUFR * ZST];   // 14112 B
    __shared__ unsigned short zB[BUFR * ZST];   // 14112 B
    __shared__ float ys[CROWS * YST];           // 25344 B  (total 53568 -> 3 blk/CU)

    const int tid = threadIdx.x;
    const int b = blockIdx.y;
    const int l0 = blockIdx.x * TILE;
    const int lane = tid & 63;
    const int wv = tid >> 6;
    const int ch = wv & 1;             // co half: co in [ch*32, ch*32+32)
    const int rh = wv >> 1;            // row half: bands rh*3 .. rh*3+2
    const int g = lane >> 4;
    const int ml = lane & 15;
    const int co = ch * 32 + 2 * ml;   // lane's adjacent co pair
    const bool edge = (blockIdx.x == 0) || (blockIdx.x == NBLK - 1);

    // valid row range: r in [rmin, rmax) <-> l in [0, LL)
    const int rmin = (blockIdx.x == 0) ? 4 : 0;
    const int rmax = min(CROWS, LL - l0 + 4);

    // zero conv-pad rows (z rows 0 and BUFR-1) of both buffers
    if (tid < 64) {
        zA[tid] = 0; zA[(BUFR - 1) * ZST + tid] = 0;
        zB[tid] = 0; zB[(BUFR - 1) * ZST + tid] = 0;
    }

    // ---- B fragments (bf16 RNE): chunk c: kw=c>>1, ci=(c&1)*32 + g*8 + j ----
    bf16x8 Bf[6][2];
#pragma unroll
    for (int c = 0; c < 6; c++) {
        const float* wp = w + (c >> 1) * (65 * CC) + (((c & 1) * 32) + g * 8) * CC + co;
#pragma unroll
        for (int j = 0; j < 8; j++) {
            float2 v = *(const float2*)(wp + j * CC);
            Bf[c][0][j] = bf16_of(v.x);
            Bf[c][1][j] = bf16_of(v.y);
        }
    }
    const float2 wt0 = *(const float2*)(w + 0 * (65 * CC) + CC * CC + co);
    const float2 wt1 = *(const float2*)(w + 1 * (65 * CC) + CC * CC + co);
    const float2 wt2 = *(const float2*)(w + 2 * (65 * CC) + CC * CC + co);
    const float2 bv  = *(const float2*)(bias + co);

    // ---- stage: y -> ys (fp32 LDS), z0 = bf16(y) -> zA; coalesced float4 ----
    const float* yrow = y_in + ((size_t)b * LL + (size_t)(l0 - 4)) * CC;
    for (int idx = tid; idx < CROWS * 16; idx += THREADS) {
        const int row = idx >> 4;
        const int c4 = (idx & 15) * 4;
        float4 v = make_float4(0.f, 0.f, 0.f, 0.f);
        if (row >= rmin && row < rmax)
            v = *(const float4*)(yrow + (size_t)row * CC + c4);
        float* yp = &ys[row * YST + c4];
        *(float2*)(yp + 0) = make_float2(v.x, v.y);
        *(float2*)(yp + 2) = make_float2(v.z, v.w);
        uint2 p;
        p.x = pack_bf16(v.x, v.y);
        p.y = pack_bf16(v.z, v.w);
        *(uint2*)&zA[(row + 1) * ZST + c4] = p;
    }
    __syncthreads();

    float2 aR[3][4];
    const float ca[4]  = {h / 6.f, h / 3.f, h / 3.f, h / 6.f};
    const float cuv[4] = {0.5f * h, 0.5f * h, h, 0.f};
    const float tof[4] = {0.f, 0.5f * h, 0.5f * h, h};

#pragma unroll 1
    for (int e = 0; e < 4; e++) {
        const unsigned short* zin = (e & 1) ? zB : zA;
        unsigned short* zout = (e & 1) ? zA : zB;
        const float t = t0 + tof[e];
        const float cacc = ca[e], cuu = cuv[e];
        const float2 tb = {t * (wt0.x + wt1.x + wt2.x) + bv.x,
                           t * (wt0.y + wt1.y + wt2.y) + bv.y};

#pragma unroll
        for (int bb = 0; bb < 3; bb++) {
            const int r0 = (rh * 3 + bb) * 16;
            f32x4 acc0 = {0.f, 0.f, 0.f, 0.f};
            f32x4 acc1 = {0.f, 0.f, 0.f, 0.f};
#pragma unroll
            for (int c = 0; c < 6; c++) {
                const int zr = r0 + ml + (c >> 1);   // data row r0+ml-1+kw -> z row +1
                const bf16x8 a =
                    *(const bf16x8*)&zin[zr * ZST + ((c & 1) * 32) + g * 8];
                acc0 = __builtin_amdgcn_mfma_f32_16x16x32_bf16(a, Bf[c][0], acc0, 0, 0, 0);
                acc1 = __builtin_amdgcn_mfma_f32_16x16x32_bf16(a, Bf[c][1], acc1, 0, 0, 0);
            }
#pragma unroll
            for (int i = 0; i < 4; i++) {
                const int r = r0 + g * 4 + i;
                float k0 = acc0[i] + tb.x;
                float k1 = acc1[i] + tb.y;
                if (edge) {
                    const int l = l0 - 4 + r;
                    if (l == 0)      { k0 -= t * wt0.x; k1 -= t * wt0.y; }
                    if (l == LL - 1) { k0 -= t * wt2.x; k1 -= t * wt2.y; }
                }
                k0 = fmaxf(k0, 0.f);
                k1 = fmaxf(k1, 0.f);
                const float2 y2 = *(const float2*)&ys[r * YST + co];
                if (e == 0) {
                    aR[bb][i].x = y2.x + cacc * k0;
                    aR[bb][i].y = y2.y + cacc * k1;
                } else {
                    aR[bb][i].x += cacc * k0;
                    aR[bb][i].y += cacc * k1;
                }
                if (e < 3) {
                    float u0 = 0.f, u1 = 0.f;
                    if (r >= rmin && r < rmax) {     // seq-boundary rows stay 0
                        u0 = y2.x + cuu * k0;
                        u1 = y2.y + cuu * k1;
                    }
                    *(unsigned*)&zout[(r + 1) * ZST + co] = pack_bf16(u0, u1);
                }
            }
        }
        if (e < 3) __syncthreads();
    }

    // ---- store central rows (r in [4, 4+TILE) and < rmax) ----
#pragma unroll
    for (int bb = 0; bb < 3; bb++) {
        const int r0 = (rh * 3 + bb) * 16;
#pragma unroll
        for (int i = 0; i < 4; i++) {
            const int r = r0 + g * 4 + i;
            if (r >= 4 && r < 4 + TILE && r < rmax) {
                const int l = l0 - 4 + r;
                *(float2*)(y_out + ((size_t)b * LL + l) * CC + co) = aR[bb][i];
            }
        }
    }
}

extern "C" void kernel_launch(void* const* d_in, const int* in_sizes, int n_in,
                              void* d_out, int out_size, void* d_ws, size_t ws_size,
                              hipStream_t stream) {
    const float* x = (const float*)d_in[0];
    const float* w = (const float*)d_in[1];
    const float* bias = (const float*)d_in[2];
    float* out = (float*)d_out;
    float* P0 = (float*)d_ws;   // 32*8192*64*4 = 67.1 MB scratch
    const float h = 1.0f / 8.0f;

    dim3 grid(NBLK, BB), block(THREADS);
    for (int s = 0; s < 8; s++) {
        const float* yin = (s == 0) ? x : ((s & 1) ? P0 : out);
        float* yout = (s & 1) ? out : P0;   // step 7 (s=7, odd) writes `out`
        step_kernel<<<grid, block, 0, stream>>>(yin, yout, w, bias, s * h, h);
    }
}